// Round 1
// baseline (347.940 us; speedup 1.0000x reference)
//
#include <hip/hip_runtime.h>
#include <cstdint>
#include <cstddef>

#define A_TOTAL 82944   // 96*96*9
#define NUM_C   80
#define NBOX    32
#define EMB_C   128
#define IDS     500
#define HW      9216    // 96*96
#define FM_W    96
#define BATCH   4

__device__ __forceinline__ float wave_sum(float v) {
#pragma unroll
    for (int o = 32; o > 0; o >>= 1) v += __shfl_down(v, o, 64);
    return v;
}

// -------- Kernel 1: IoU assignment + focal cls loss + smooth-L1 reg loss ----
// grid: (A_TOTAL/64, B), block: 256.
// acc layout per image b (8 floats): [0]=num_pos [1]=cls_sum [2]=reg_sum
//                                    [3]=id_sum  [4]=valid_sum
__global__ __launch_bounds__(256) void assign_focal_reg_kernel(
    const float* __restrict__ cls, const float* __restrict__ reg,
    const float* __restrict__ anchors, const float* __restrict__ boxes,
    const int* __restrict__ labels, float* __restrict__ acc)
{
    const int b   = blockIdx.y;
    const int a0  = blockIdx.x * 64;
    const int tid = threadIdx.x;

    __shared__ float4 sbox[NBOX];
    __shared__ int    slab[NBOX];
    __shared__ int    sstate[64];      // (flag<<8)|label ; flag 0=ignore 1=neg 2=pos
    __shared__ float  sred[3][4];

    if (tid < NBOX) {
        sbox[tid] = ((const float4*)boxes)[b * NBOX + tid];
        slab[tid] = labels[b * NBOX + tid];
    }
    __syncthreads();

    float reg_part = 0.f, np_part = 0.f;
    if (tid < 64) {
        const int a = a0 + tid;
        const float4 an = ((const float4*)anchors)[a];   // (y1,x1,y2,x2)
        const float area_a = (an.z - an.x) * (an.w - an.y);
        float best = -1.f; int arg = 0;
#pragma unroll
        for (int n = 0; n < NBOX; ++n) {
            const float4 bx = sbox[n];                   // (x1,y1,x2,y2)
            float iw = fmaxf(fminf(an.w, bx.z) - fmaxf(an.y, bx.x), 0.f);
            float ih = fmaxf(fminf(an.z, bx.w) - fmaxf(an.x, bx.y), 0.f);
            float inter = iw * ih;
            float area_b = (bx.z - bx.x) * (bx.w - bx.y);
            float ua  = fmaxf(area_a + area_b - inter, 1e-8f);
            float iou = inter / ua;
            if (iou > best) { best = iou; arg = n; }     // strict > : first max
        }
        const bool pos = best >= 0.5f;
        const bool neg = best < 0.4f;
        const int flag = pos ? 2 : (neg ? 1 : 0);
        sstate[tid] = (flag << 8) | slab[arg];
        if (pos) {
            np_part = 1.f;
            const float4 ab = sbox[arg];
            float gw  = ab.z - ab.x, gh = ab.w - ab.y;
            float gcx = ab.x + 0.5f * gw, gcy = ab.y + 0.5f * gh;
            gw = fmaxf(gw, 1.f); gh = fmaxf(gh, 1.f);
            const float aw  = an.w - an.y, ah = an.z - an.x;
            const float acx = an.y + 0.5f * aw, acy = an.x + 0.5f * ah;
            const float t0 = (gcy - acy) / ah;
            const float t1 = (gcx - acx) / aw;
            const float t2 = logf(gh / ah);
            const float t3 = logf(gw / aw);
            const float4 rg = ((const float4*)reg)[(size_t)b * A_TOTAL + a];
            float dd[4] = { fabsf(t0 - rg.x), fabsf(t1 - rg.y),
                            fabsf(t2 - rg.z), fabsf(t3 - rg.w) };
#pragma unroll
            for (int k = 0; k < 4; ++k) {
                const float d = dd[k];
                reg_part += (d <= (1.f/9.f)) ? (4.5f * d * d) : (d - (0.5f/9.f));
            }
        }
    }
    __syncthreads();

    // Focal loss over this block's 64 anchors x 80 classes = 1280 float4.
    const float4* crow =
        (const float4*)(cls + ((size_t)b * A_TOTAL + a0) * NUM_C);
    const float LO = 1e-4f;
    const float HI = (float)(1.0 - 1e-4);
    float cls_part = 0.f;
#pragma unroll
    for (int k = 0; k < 5; ++k) {
        const int f    = tid + k * 256;
        const int row  = f / 20;          // anchor within block
        const int col4 = f - row * 20;    // float4 within row
        const int st   = sstate[row];
        const int flag = st >> 8;
        if (flag != 0) {
            const int lab = st & 0xff;
            const float4 p4 = crow[f];
            const float pv[4] = { p4.x, p4.y, p4.z, p4.w };
            const int cbase = col4 * 4;
#pragma unroll
            for (int j = 0; j < 4; ++j) {
                const float p = fminf(fmaxf(pv[j], LO), HI);
                if (flag == 2 && (cbase + j) == lab) {
                    const float q = 1.f - p;
                    cls_part += 0.25f * q * q * (-__logf(p));     // t=1 term
                } else {
                    cls_part += 0.75f * p * p * (-__logf(1.f - p)); // t=0 term
                }
            }
        }
    }

    // block reduction (4 waves)
    const float w0 = wave_sum(cls_part);
    const float w1 = wave_sum(reg_part);
    const float w2 = wave_sum(np_part);
    const int wid = tid >> 6, lane = tid & 63;
    if (lane == 0) { sred[0][wid] = w0; sred[1][wid] = w1; sred[2][wid] = w2; }
    __syncthreads();
    if (tid == 0) {
        atomicAdd(&acc[b * 8 + 0], sred[2][0] + sred[2][1] + sred[2][2] + sred[2][3]);
        atomicAdd(&acc[b * 8 + 1], sred[0][0] + sred[0][1] + sred[0][2] + sred[0][3]);
        atomicAdd(&acc[b * 8 + 2], sred[1][0] + sred[1][1] + sred[1][2] + sred[1][3]);
    }
}

// -------- Kernel 2: ReID tracking loss ------------------------------------
// grid: (NBOX, B), block: 256.
__global__ __launch_bounds__(256) void reid_kernel(
    const float* __restrict__ emb, const float* __restrict__ boxes,
    const int* __restrict__ reids, const float* __restrict__ Wt,
    const float* __restrict__ bt, const float* __restrict__ emb_scale,
    float* __restrict__ acc)
{
    const int b   = blockIdx.y;
    const int n   = blockIdx.x;
    const int tid = threadIdx.x;

    __shared__ float sfeat[EMB_C];
    __shared__ float slog[IDS];
    __shared__ float sred[4];
    __shared__ float sscale;
    __shared__ float smax;

    const float4 bx = ((const float4*)boxes)[b * NBOX + n];
    const int cx = (int)floorf((bx.x + bx.z) * 0.125f);
    const int cy = (int)floorf((bx.y + bx.w) * 0.125f);
    const int ind = cy * FM_W + cx;

    float sq = 0.f;
    if (tid < EMB_C) {
        const float v = emb[((size_t)b * EMB_C + tid) * HW + ind];
        sfeat[tid] = v;
        sq = v * v;
    }
    const float wsq = wave_sum(sq);
    if ((tid & 63) == 0) sred[tid >> 6] = wsq;
    __syncthreads();
    if (tid == 0) {
        const float nrm = sqrtf(sred[0] + sred[1]);
        sscale = emb_scale[0] / fmaxf(nrm, 1e-12f);
    }
    __syncthreads();
    if (tid < EMB_C) sfeat[tid] *= sscale;
    __syncthreads();

    for (int j = tid; j < IDS; j += 256) {
        float al = bt[j];
#pragma unroll 8
        for (int c = 0; c < EMB_C; ++c) al += sfeat[c] * Wt[c * IDS + j];
        slog[j] = al;
    }
    __syncthreads();

    float m = -1e30f;
    for (int j = tid; j < IDS; j += 256) m = fmaxf(m, slog[j]);
#pragma unroll
    for (int o = 32; o > 0; o >>= 1) m = fmaxf(m, __shfl_down(m, o, 64));
    if ((tid & 63) == 0) sred[tid >> 6] = m;
    __syncthreads();
    if (tid == 0) smax = fmaxf(fmaxf(sred[0], sred[1]), fmaxf(sred[2], sred[3]));
    __syncthreads();
    m = smax;

    float se = 0.f;
    for (int j = tid; j < IDS; j += 256) se += expf(slog[j] - m);
    se = wave_sum(se);
    if ((tid & 63) == 0) sred[tid >> 6] = se;
    __syncthreads();
    if (tid == 0) {
        const float sum = sred[0] + sred[1] + sred[2] + sred[3];
        const int rid = reids[b * NBOX + n];
        const float valid = (rid >= 0) ? 1.f : 0.f;
        const int t = rid < 0 ? 0 : rid;
        const float ce = -(slog[t] - m - logf(sum));
        atomicAdd(&acc[b * 8 + 3], ce * valid);
        atomicAdd(&acc[b * 8 + 4], valid);
    }
}

// -------- Kernel 3: finalize ------------------------------------------------
__global__ void finalize_kernel(const float* __restrict__ acc,
                                float* __restrict__ out)
{
    if (threadIdx.x == 0) {
        float cls_m = 0.f, reg_m = 0.f, trk_m = 0.f;
#pragma unroll
        for (int b = 0; b < BATCH; ++b) {
            const float np = acc[b * 8 + 0];
            cls_m += acc[b * 8 + 1] / fmaxf(np, 1.f);
            reg_m += acc[b * 8 + 2] / fmaxf(np * 4.f, 1.f);
            const float id_loss = acc[b * 8 + 3] / fmaxf(acc[b * 8 + 4], 1.f);
            trk_m += (np > 0.f) ? id_loss : 0.f;
        }
        out[0] = cls_m * 0.25f;
        out[1] = reg_m * 0.25f * 50.f;
        out[2] = trk_m * 0.25f;
    }
}

extern "C" void kernel_launch(void* const* d_in, const int* in_sizes, int n_in,
                              void* d_out, int out_size, void* d_ws, size_t ws_size,
                              hipStream_t stream) {
    const float* cls      = (const float*)d_in[0];
    const float* reg      = (const float*)d_in[1];
    const float* anchors  = (const float*)d_in[2];
    const float* emb      = (const float*)d_in[3];
    const float* boxes    = (const float*)d_in[4];
    const int*   labels   = (const int*)d_in[5];
    const int*   reids    = (const int*)d_in[6];
    const float* Wt       = (const float*)d_in[7];
    const float* bt       = (const float*)d_in[8];
    const float* escale   = (const float*)d_in[9];
    float* out = (float*)d_out;
    float* acc = (float*)d_ws;   // BATCH*8 floats

    hipMemsetAsync(acc, 0, BATCH * 8 * sizeof(float), stream);

    dim3 g1(A_TOTAL / 64, BATCH), blk(256);
    assign_focal_reg_kernel<<<g1, blk, 0, stream>>>(cls, reg, anchors, boxes,
                                                    labels, acc);
    dim3 g2(NBOX, BATCH);
    reid_kernel<<<g2, blk, 0, stream>>>(emb, boxes, reids, Wt, bt, escale, acc);
    finalize_kernel<<<1, 64, 0, stream>>>(acc, out);
}

// Round 2
// 200.665 us; speedup vs baseline: 1.7339x; 1.7339x over previous
//
#include <hip/hip_runtime.h>
#include <cstdint>
#include <cstddef>

#define A_TOTAL 82944   // 96*96*9
#define NUM_C   80
#define NBOX    32
#define EMB_C   128
#define IDS     500
#define HW      9216    // 96*96
#define FM_W    96
#define BATCH   4
#define ABLK    256                 // anchors per block (kernel 1)
#define NBLK    (A_TOTAL / ABLK)    // 324 blocks per image
#define REID_OFF 8192               // float offset of reid partials in ws

__device__ __forceinline__ float wave_sum(float v) {
#pragma unroll
    for (int o = 32; o > 0; o >>= 1) v += __shfl_down(v, o, 64);
    return v;
}
__device__ __forceinline__ float wave_max(float v) {
#pragma unroll
    for (int o = 32; o > 0; o >>= 1) v = fmaxf(v, __shfl_down(v, o, 64));
    return v;
}

// -------- Kernel 1: IoU assignment + focal cls loss + smooth-L1 reg loss ----
// grid: (NBLK, B), block: 256. NO atomics: per-block partials -> ws.
// part[(b*NBLK + bx)*4 + {0,1,2}] = {num_pos, cls_sum, reg_sum}
__global__ __launch_bounds__(256) void assign_focal_reg_kernel(
    const float* __restrict__ cls, const float* __restrict__ reg,
    const float* __restrict__ anchors, const float* __restrict__ boxes,
    const int* __restrict__ labels, float* __restrict__ part)
{
    const int b   = blockIdx.y;
    const int a0  = blockIdx.x * ABLK;
    const int tid = threadIdx.x;

    __shared__ float4 sbox[NBOX];
    __shared__ int    slab[NBOX];
    __shared__ int    sstate[ABLK];    // (flag<<8)|label ; flag 0=ignore 1=neg 2=pos
    __shared__ float  sred[3][4];

    if (tid < NBOX) {
        sbox[tid] = ((const float4*)boxes)[b * NBOX + tid];
        slab[tid] = labels[b * NBOX + tid];
    }
    __syncthreads();

    // ---- per-thread anchor assignment (all 256 threads active) ----
    const int a = a0 + tid;
    const float4 an = ((const float4*)anchors)[a];       // (y1,x1,y2,x2)
    const float area_a = (an.z - an.x) * (an.w - an.y);
    float best = -1.f; int arg = 0;
#pragma unroll
    for (int n = 0; n < NBOX; ++n) {
        const float4 bx = sbox[n];                       // (x1,y1,x2,y2)
        float iw = fmaxf(fminf(an.w, bx.z) - fmaxf(an.y, bx.x), 0.f);
        float ih = fmaxf(fminf(an.z, bx.w) - fmaxf(an.x, bx.y), 0.f);
        float inter = iw * ih;
        float area_b = (bx.z - bx.x) * (bx.w - bx.y);
        float ua  = fmaxf(area_a + area_b - inter, 1e-8f);
        float iou = inter / ua;
        if (iou > best) { best = iou; arg = n; }         // strict > : first max
    }
    const bool pos = best >= 0.5f;
    const bool neg = best < 0.4f;
    const int flag = pos ? 2 : (neg ? 1 : 0);
    sstate[tid] = (flag << 8) | slab[arg];

    float reg_part = 0.f, np_part = 0.f;
    if (pos) {
        np_part = 1.f;
        const float4 ab = sbox[arg];
        float gw  = ab.z - ab.x, gh = ab.w - ab.y;
        float gcx = ab.x + 0.5f * gw, gcy = ab.y + 0.5f * gh;
        gw = fmaxf(gw, 1.f); gh = fmaxf(gh, 1.f);
        const float aw  = an.w - an.y, ah = an.z - an.x;
        const float acx = an.y + 0.5f * aw, acy = an.x + 0.5f * ah;
        const float t0 = (gcy - acy) / ah;
        const float t1 = (gcx - acx) / aw;
        const float t2 = logf(gh / ah);
        const float t3 = logf(gw / aw);
        const float4 rg = ((const float4*)reg)[(size_t)b * A_TOTAL + a];
        float dd[4] = { fabsf(t0 - rg.x), fabsf(t1 - rg.y),
                        fabsf(t2 - rg.z), fabsf(t3 - rg.w) };
#pragma unroll
        for (int k = 0; k < 4; ++k) {
            const float d = dd[k];
            reg_part += (d <= (1.f/9.f)) ? (4.5f * d * d) : (d - (0.5f/9.f));
        }
    }
    __syncthreads();

    // ---- focal loss: 256 anchors x 80 classes = 5120 float4, coalesced ----
    const float4* crow =
        (const float4*)(cls + ((size_t)b * A_TOTAL + a0) * NUM_C);
    const float LO = 1e-4f;
    const float HI = (float)(1.0 - 1e-4);
    float cls_part = 0.f;
#pragma unroll
    for (int k = 0; k < 20; ++k) {
        const int f    = tid + k * 256;
        const int row  = f / 20;          // anchor within block
        const int col4 = f - row * 20;    // float4 within row
        const float4 p4 = crow[f];        // unconditional -> pipelines freely
        const int st   = sstate[row];
        const int flag2 = st >> 8;
        const int lab   = st & 0xff;
        const int cbase = col4 * 4;
        const float pv[4] = { p4.x, p4.y, p4.z, p4.w };
#pragma unroll
        for (int j = 0; j < 4; ++j) {
            const float p = fminf(fmaxf(pv[j], LO), HI);
            const bool one = (flag2 == 2) && ((cbase + j) == lab);
            // t=1: 0.25*(1-p)^2*(-log p); t=0: 0.75*p^2*(-log(1-p))
            // unified: af*w^2*(-log(1-w)), w = one ? 1-p : p  -> single log
            const float w  = one ? (1.f - p) : p;
            const float af = one ? 0.25f : 0.75f;
            const float t  = af * w * w * (-__logf(1.f - w));
            cls_part += (flag2 != 0) ? t : 0.f;
        }
    }

    // ---- block reduction, plain store (no atomics) ----
    const float w0 = wave_sum(cls_part);
    const float w1 = wave_sum(reg_part);
    const float w2 = wave_sum(np_part);
    const int wid = tid >> 6, lane = tid & 63;
    if (lane == 0) { sred[0][wid] = w0; sred[1][wid] = w1; sred[2][wid] = w2; }
    __syncthreads();
    if (tid == 0) {
        float* o = part + ((size_t)b * NBLK + blockIdx.x) * 4;
        o[0] = sred[2][0] + sred[2][1] + sred[2][2] + sred[2][3];  // num_pos
        o[1] = sred[0][0] + sred[0][1] + sred[0][2] + sred[0][3];  // cls
        o[2] = sred[1][0] + sred[1][1] + sred[1][2] + sred[1][3];  // reg
    }
}

// -------- Kernel 2: ReID tracking loss ------------------------------------
// grid: (NBOX, B), block: 512. Writes {ce*valid, valid} -> ws (no atomics).
__global__ __launch_bounds__(512) void reid_kernel(
    const float* __restrict__ emb, const float* __restrict__ boxes,
    const int* __restrict__ reids, const float* __restrict__ Wt,
    const float* __restrict__ bt, const float* __restrict__ emb_scale,
    float* __restrict__ ws)
{
    const int b   = blockIdx.y;
    const int n   = blockIdx.x;
    const int tid = threadIdx.x;

    __shared__ float sfeat[EMB_C];
    __shared__ float slog[IDS];
    __shared__ float sred[8];
    __shared__ float sb[2];            // [0]=scale [1]=max

    const float4 bx = ((const float4*)boxes)[b * NBOX + n];
    const int cx = (int)floorf((bx.x + bx.z) * 0.125f);
    const int cy = (int)floorf((bx.y + bx.w) * 0.125f);
    const int ind = cy * FM_W + cx;

    float sq = 0.f;
    if (tid < EMB_C) {
        const float v = emb[((size_t)b * EMB_C + tid) * HW + ind];
        sfeat[tid] = v;
        sq = v * v;
    }
    const float wsq = wave_sum(sq);
    if ((tid & 63) == 0) sred[tid >> 6] = wsq;
    __syncthreads();
    if (tid == 0) {
        const float nrm = sqrtf(sred[0] + sred[1]);
        sb[0] = emb_scale[0] / fmaxf(nrm, 1e-12f);
    }
    __syncthreads();
    if (tid < EMB_C) sfeat[tid] *= sb[0];
    __syncthreads();

    // logits: thread j owns output j (j < 500); Wt[c*IDS+j] coalesced in j
    if (tid < IDS) {
        float al = bt[tid];
#pragma unroll 16
        for (int c = 0; c < EMB_C; ++c) al += sfeat[c] * Wt[c * IDS + tid];
        slog[tid] = al;
    }
    __syncthreads();

    float m = (tid < IDS) ? slog[tid] : -1e30f;
    m = wave_max(m);
    if ((tid & 63) == 0) sred[tid >> 6] = m;
    __syncthreads();
    if (tid == 0) {
        float mm = sred[0];
#pragma unroll
        for (int i = 1; i < 8; ++i) mm = fmaxf(mm, sred[i]);
        sb[1] = mm;
    }
    __syncthreads();
    m = sb[1];

    float se = (tid < IDS) ? expf(slog[tid] - m) : 0.f;
    se = wave_sum(se);
    if ((tid & 63) == 0) sred[tid >> 6] = se;
    __syncthreads();
    if (tid == 0) {
        float sum = 0.f;
#pragma unroll
        for (int i = 0; i < 8; ++i) sum += sred[i];
        const int rid = reids[b * NBOX + n];
        const float valid = (rid >= 0) ? 1.f : 0.f;
        const int t = rid < 0 ? 0 : rid;
        const float ce = -(slog[t] - m - logf(sum));
        float* o = ws + REID_OFF + ((size_t)b * NBOX + n) * 2;
        o[0] = ce * valid;
        o[1] = valid;
    }
}

// -------- Kernel 3: finalize (1 block, wave w = image b) -------------------
__global__ __launch_bounds__(256) void finalize_kernel(
    const float* __restrict__ ws, float* __restrict__ out)
{
    __shared__ float s[BATCH][3];
    const int tid  = threadIdx.x;
    const int b    = tid >> 6;
    const int lane = tid & 63;

    float np = 0.f, cl = 0.f, rg = 0.f, ce = 0.f, va = 0.f;
    for (int i = lane; i < NBLK; i += 64) {
        const float* p = ws + ((size_t)b * NBLK + i) * 4;
        np += p[0]; cl += p[1]; rg += p[2];
    }
    if (lane < NBOX) {
        const float* r = ws + REID_OFF + ((size_t)b * NBOX + lane) * 2;
        ce = r[0]; va = r[1];
    }
    np = wave_sum(np); cl = wave_sum(cl); rg = wave_sum(rg);
    ce = wave_sum(ce); va = wave_sum(va);
    if (lane == 0) {
        const float cls_l = cl / fmaxf(np, 1.f);
        const float reg_l = rg / fmaxf(np * 4.f, 1.f);
        const float id_l  = ce / fmaxf(va, 1.f);
        s[b][0] = cls_l;
        s[b][1] = reg_l;
        s[b][2] = (np > 0.f) ? id_l : 0.f;
    }
    __syncthreads();
    if (tid == 0) {
        out[0] = (s[0][0] + s[1][0] + s[2][0] + s[3][0]) * 0.25f;
        out[1] = (s[0][1] + s[1][1] + s[2][1] + s[3][1]) * 0.25f * 50.f;
        out[2] = (s[0][2] + s[1][2] + s[2][2] + s[3][2]) * 0.25f;
    }
}

extern "C" void kernel_launch(void* const* d_in, const int* in_sizes, int n_in,
                              void* d_out, int out_size, void* d_ws, size_t ws_size,
                              hipStream_t stream) {
    const float* cls      = (const float*)d_in[0];
    const float* reg      = (const float*)d_in[1];
    const float* anchors  = (const float*)d_in[2];
    const float* emb      = (const float*)d_in[3];
    const float* boxes    = (const float*)d_in[4];
    const int*   labels   = (const int*)d_in[5];
    const int*   reids    = (const int*)d_in[6];
    const float* Wt       = (const float*)d_in[7];
    const float* bt       = (const float*)d_in[8];
    const float* escale   = (const float*)d_in[9];
    float* out = (float*)d_out;
    float* ws  = (float*)d_ws;

    dim3 g1(NBLK, BATCH);
    assign_focal_reg_kernel<<<g1, dim3(256), 0, stream>>>(cls, reg, anchors,
                                                          boxes, labels, ws);
    dim3 g2(NBOX, BATCH);
    reid_kernel<<<g2, dim3(512), 0, stream>>>(emb, boxes, reids, Wt, bt,
                                              escale, ws);
    finalize_kernel<<<1, 256, 0, stream>>>(ws, out);
}

// Round 4
// 197.953 us; speedup vs baseline: 1.7577x; 1.0137x over previous
//
#include <hip/hip_runtime.h>
#include <cstdint>
#include <cstddef>

#define A_TOTAL 82944   // 96*96*9
#define NUM_C   80
#define NBOX    32
#define EMB_C   128
#define IDS     500
#define HW      9216    // 96*96
#define FM_W    96
#define BATCH   4
#define ABLK    256                 // anchors per block (kernel 1)
#define NBLK    (A_TOTAL / ABLK)    // 324 blocks per image
#define REID_OFF 8192               // float offset of reid partials in ws

typedef float floatx4 __attribute__((ext_vector_type(4)));  // nontemporal-compatible

__device__ __forceinline__ float wave_sum(float v) {
#pragma unroll
    for (int o = 32; o > 0; o >>= 1) v += __shfl_down(v, o, 64);
    return v;
}
__device__ __forceinline__ float wave_max(float v) {
#pragma unroll
    for (int o = 32; o > 0; o >>= 1) v = fmaxf(v, __shfl_down(v, o, 64));
    return v;
}

// -------- Kernel 1: IoU assignment + focal cls loss + smooth-L1 reg loss ----
// grid: (NBLK, B), block: 256. Per-block partials -> ws (no atomics).
// part[(b*NBLK + bx)*4 + {0,1,2}] = {num_pos, cls_sum, reg_sum}
__global__ __launch_bounds__(256) void assign_focal_reg_kernel(
    const float* __restrict__ cls, const float* __restrict__ reg,
    const float* __restrict__ anchors, const float* __restrict__ boxes,
    const int* __restrict__ labels, float* __restrict__ part)
{
    const int b   = blockIdx.y;
    const int a0  = blockIdx.x * ABLK;
    const int tid = threadIdx.x;

    __shared__ float4 sbox[NBOX];
    __shared__ int    slab[NBOX];
    __shared__ int    slabenc[ABLK];   // label if pos else -1 (never matches)
    __shared__ float  sgate[ABLK];     // 1.0 if pos|neg else 0.0
    __shared__ float  sred[3][4];

    if (tid < NBOX) {
        sbox[tid] = ((const float4*)boxes)[b * NBOX + tid];
        slab[tid] = labels[b * NBOX + tid];
    }
    __syncthreads();

    // ---- per-thread anchor assignment (all 256 threads active) ----
    const int a = a0 + tid;
    const float4 an = ((const float4*)anchors)[a];       // (y1,x1,y2,x2)
    const float area_a = (an.z - an.x) * (an.w - an.y);
    float best = -1.f; int arg = 0;
#pragma unroll
    for (int n = 0; n < NBOX; ++n) {
        const float4 bx = sbox[n];                       // (x1,y1,x2,y2)
        float iw = fmaxf(fminf(an.w, bx.z) - fmaxf(an.y, bx.x), 0.f);
        float ih = fmaxf(fminf(an.z, bx.w) - fmaxf(an.x, bx.y), 0.f);
        float inter = iw * ih;
        float area_b = (bx.z - bx.x) * (bx.w - bx.y);
        float ua  = fmaxf(area_a + area_b - inter, 1e-8f);
        float iou = inter / ua;
        if (iou > best) { best = iou; arg = n; }         // strict > : first max
    }
    const bool pos = best >= 0.5f;
    const bool neg = best < 0.4f;
    slabenc[tid] = pos ? slab[arg] : -1;
    sgate[tid]   = (pos || neg) ? 1.f : 0.f;

    float reg_part = 0.f, np_part = 0.f;
    if (pos) {
        np_part = 1.f;
        const float4 ab = sbox[arg];
        float gw  = ab.z - ab.x, gh = ab.w - ab.y;
        float gcx = ab.x + 0.5f * gw, gcy = ab.y + 0.5f * gh;
        gw = fmaxf(gw, 1.f); gh = fmaxf(gh, 1.f);
        const float aw  = an.w - an.y, ah = an.z - an.x;
        const float acx = an.y + 0.5f * aw, acy = an.x + 0.5f * ah;
        const float t0 = (gcy - acy) / ah;
        const float t1 = (gcx - acx) / aw;
        const float t2 = logf(gh / ah);
        const float t3 = logf(gw / aw);
        const float4 rg = ((const float4*)reg)[(size_t)b * A_TOTAL + a];
        float dd[4] = { fabsf(t0 - rg.x), fabsf(t1 - rg.y),
                        fabsf(t2 - rg.z), fabsf(t3 - rg.w) };
#pragma unroll
        for (int k = 0; k < 4; ++k) {
            const float d = dd[k];
            reg_part += (d <= (1.f/9.f)) ? (4.5f * d * d) : (d - (0.5f/9.f));
        }
    }
    __syncthreads();

    // ---- focal loss: 256 anchors x 80 classes = 5120 float4 per block.
    // 4 groups x 5 nontemporal float4 loads in flight per thread.
    const floatx4* crow =
        (const floatx4*)(cls + ((size_t)b * A_TOTAL + a0) * NUM_C);
    const float LO = 1e-4f;
    const float HI = (float)(1.0 - 1e-4);
    float cls_part = 0.f;
#pragma unroll
    for (int g = 0; g < 4; ++g) {
        floatx4 buf[5];
#pragma unroll
        for (int i = 0; i < 5; ++i) {
            const int f = tid + (g * 5 + i) * 256;
            buf[i] = __builtin_nontemporal_load(&crow[f]);
        }
#pragma unroll
        for (int i = 0; i < 5; ++i) {
            const int f    = tid + (g * 5 + i) * 256;
            const int row  = f / 20;          // anchor within block
            const int col4 = f - row * 20;    // float4 within row
            const int rel  = slabenc[row] - col4 * 4;  // one-hot lane in [0,4)
            const float gate = sgate[row];
            const float pv[4] = { buf[i].x, buf[i].y, buf[i].z, buf[i].w };
            float acc4 = 0.f;
#pragma unroll
            for (int j = 0; j < 4; ++j) {
                const float p  = fminf(fmaxf(pv[j], LO), HI);
                const bool one = (rel == j);
                // t=1: 0.25*(1-p)^2*(-log p); t=0: 0.75*p^2*(-log(1-p))
                // unified: af*w^2*(-log(1-w)), w = one ? 1-p : p
                const float w  = one ? (1.f - p) : p;
                const float af = one ? 0.25f : 0.75f;
                acc4 += af * w * w * (-__logf(1.f - w));
            }
            cls_part = fmaf(acc4, gate, cls_part);
        }
    }

    // ---- block reduction, plain store (no atomics) ----
    const float w0 = wave_sum(cls_part);
    const float w1 = wave_sum(reg_part);
    const float w2 = wave_sum(np_part);
    const int wid = tid >> 6, lane = tid & 63;
    if (lane == 0) { sred[0][wid] = w0; sred[1][wid] = w1; sred[2][wid] = w2; }
    __syncthreads();
    if (tid == 0) {
        float* o = part + ((size_t)b * NBLK + blockIdx.x) * 4;
        o[0] = sred[2][0] + sred[2][1] + sred[2][2] + sred[2][3];  // num_pos
        o[1] = sred[0][0] + sred[0][1] + sred[0][2] + sred[0][3];  // cls
        o[2] = sred[1][0] + sred[1][1] + sred[1][2] + sred[1][3];  // reg
    }
}

// -------- Kernel 2: ReID tracking loss ------------------------------------
// grid: (NBOX, B), block: 512. Writes {ce*valid, valid} -> ws (no atomics).
__global__ __launch_bounds__(512) void reid_kernel(
    const float* __restrict__ emb, const float* __restrict__ boxes,
    const int* __restrict__ reids, const float* __restrict__ Wt,
    const float* __restrict__ bt, const float* __restrict__ emb_scale,
    float* __restrict__ ws)
{
    const int b   = blockIdx.y;
    const int n   = blockIdx.x;
    const int tid = threadIdx.x;

    __shared__ float sfeat[EMB_C];
    __shared__ float slog[IDS];
    __shared__ float sred[8];
    __shared__ float sb[2];            // [0]=scale [1]=max

    const float4 bx = ((const float4*)boxes)[b * NBOX + n];
    const int cx = (int)floorf((bx.x + bx.z) * 0.125f);
    const int cy = (int)floorf((bx.y + bx.w) * 0.125f);
    const int ind = cy * FM_W + cx;

    float sq = 0.f;
    if (tid < EMB_C) {
        const float v = emb[((size_t)b * EMB_C + tid) * HW + ind];
        sfeat[tid] = v;
        sq = v * v;
    }
    const float wsq = wave_sum(sq);
    if ((tid & 63) == 0) sred[tid >> 6] = wsq;
    __syncthreads();
    if (tid == 0) {
        const float nrm = sqrtf(sred[0] + sred[1]);
        sb[0] = emb_scale[0] / fmaxf(nrm, 1e-12f);
    }
    __syncthreads();
    if (tid < EMB_C) sfeat[tid] *= sb[0];
    __syncthreads();

    // logits: thread j owns output j (j < 500); Wt[c*IDS+j] coalesced in j
    if (tid < IDS) {
        float al = bt[tid];
#pragma unroll 16
        for (int c = 0; c < EMB_C; ++c) al += sfeat[c] * Wt[c * IDS + tid];
        slog[tid] = al;
    }
    __syncthreads();

    float m = (tid < IDS) ? slog[tid] : -1e30f;
    m = wave_max(m);
    if ((tid & 63) == 0) sred[tid >> 6] = m;
    __syncthreads();
    if (tid == 0) {
        float mm = sred[0];
#pragma unroll
        for (int i = 1; i < 8; ++i) mm = fmaxf(mm, sred[i]);
        sb[1] = mm;
    }
    __syncthreads();
    m = sb[1];

    float se = (tid < IDS) ? expf(slog[tid] - m) : 0.f;
    se = wave_sum(se);
    if ((tid & 63) == 0) sred[tid >> 6] = se;
    __syncthreads();
    if (tid == 0) {
        float sum = 0.f;
#pragma unroll
        for (int i = 0; i < 8; ++i) sum += sred[i];
        const int rid = reids[b * NBOX + n];
        const float valid = (rid >= 0) ? 1.f : 0.f;
        const int t = rid < 0 ? 0 : rid;
        const float ce = -(slog[t] - m - logf(sum));
        float* o = ws + REID_OFF + ((size_t)b * NBOX + n) * 2;
        o[0] = ce * valid;
        o[1] = valid;
    }
}

// -------- Kernel 3: finalize (1 block, wave w = image b) -------------------
__global__ __launch_bounds__(256) void finalize_kernel(
    const float* __restrict__ ws, float* __restrict__ out)
{
    __shared__ float s[BATCH][3];
    const int tid  = threadIdx.x;
    const int b    = tid >> 6;
    const int lane = tid & 63;

    float np = 0.f, cl = 0.f, rg = 0.f, ce = 0.f, va = 0.f;
    for (int i = lane; i < NBLK; i += 64) {
        const float* p = ws + ((size_t)b * NBLK + i) * 4;
        np += p[0]; cl += p[1]; rg += p[2];
    }
    if (lane < NBOX) {
        const float* r = ws + REID_OFF + ((size_t)b * NBOX + lane) * 2;
        ce = r[0]; va = r[1];
    }
    np = wave_sum(np); cl = wave_sum(cl); rg = wave_sum(rg);
    ce = wave_sum(ce); va = wave_sum(va);
    if (lane == 0) {
        const float cls_l = cl / fmaxf(np, 1.f);
        const float reg_l = rg / fmaxf(np * 4.f, 1.f);
        const float id_l  = ce / fmaxf(va, 1.f);
        s[b][0] = cls_l;
        s[b][1] = reg_l;
        s[b][2] = (np > 0.f) ? id_l : 0.f;
    }
    __syncthreads();
    if (tid == 0) {
        out[0] = (s[0][0] + s[1][0] + s[2][0] + s[3][0]) * 0.25f;
        out[1] = (s[0][1] + s[1][1] + s[2][1] + s[3][1]) * 0.25f * 50.f;
        out[2] = (s[0][2] + s[1][2] + s[2][2] + s[3][2]) * 0.25f;
    }
}

extern "C" void kernel_launch(void* const* d_in, const int* in_sizes, int n_in,
                              void* d_out, int out_size, void* d_ws, size_t ws_size,
                              hipStream_t stream) {
    const float* cls      = (const float*)d_in[0];
    const float* reg      = (const float*)d_in[1];
    const float* anchors  = (const float*)d_in[2];
    const float* emb      = (const float*)d_in[3];
    const float* boxes    = (const float*)d_in[4];
    const int*   labels   = (const int*)d_in[5];
    const int*   reids    = (const int*)d_in[6];
    const float* Wt       = (const float*)d_in[7];
    const float* bt       = (const float*)d_in[8];
    const float* escale   = (const float*)d_in[9];
    float* out = (float*)d_out;
    float* ws  = (float*)d_ws;

    dim3 g1(NBLK, BATCH);
    assign_focal_reg_kernel<<<g1, dim3(256), 0, stream>>>(cls, reg, anchors,
                                                          boxes, labels, ws);
    dim3 g2(NBOX, BATCH);
    reid_kernel<<<g2, dim3(512), 0, stream>>>(emb, boxes, reids, Wt, bt,
                                              escale, ws);
    finalize_kernel<<<1, 256, 0, stream>>>(ws, out);
}